// Round 1
// baseline (636.918 us; speedup 1.0000x reference)
//
#include <hip/hip_runtime.h>
#include <hip/hip_fp16.h>

#define HIDDEN 2048
#define INTER  1408
#define NEXP   8
#define NTOK   2048

typedef _Float16 f16;
typedef _Float16 f16x2 __attribute__((ext_vector_type(2)));
typedef _Float16 f16x4 __attribute__((ext_vector_type(4)));
typedef _Float16 f16x8 __attribute__((ext_vector_type(8)));
typedef float f32x4 __attribute__((ext_vector_type(4)));

static __device__ __forceinline__ f16x2 pkrtz(float a, float b) {
  return __builtin_bit_cast(f16x2, __builtin_amdgcn_cvt_pkrtz(a, b));
}

// async 16B global -> LDS. Dest = wave-uniform base + lane*16 (HW rule).
static __device__ __forceinline__ void gl_lds16(const f16* g, f16* l) {
  __builtin_amdgcn_global_load_lds(
      (const __attribute__((address_space(1))) void*)g,
      (__attribute__((address_space(3))) void*)l, 16, 0, 0);
}

// ---------------- workspace layouts ----------------------------------------
#define SZ_LIST (NEXP*NTOK*4)
#define SZ_WGT  (NEXP*NTOK*4)
#define SZ_MAP  (NTOK*16)
#define SZ_WPR  (NTOK*8)
// fallback path
#define OP_CNT   0
#define OP_OFFS  256
#define OP_LIST  512
#define OP_WGT   (OP_LIST + SZ_LIST)
#define OP_MAP   (OP_WGT + SZ_WGT)
#define OP_WPR   (OP_MAP + SZ_MAP)
#define OP_XH    (OP_WPR + SZ_WPR)
#define OP_H     (OP_XH + (size_t)NTOK*HIDDEN*2)
#define OP_END   (OP_H + (size_t)2*NTOK*INTER*2)
// fast path (no f16 weight copies any more: B is reg-staged from fp32 in-GEMM)
#define NP_CNT   0
#define NP_OFFS  256
#define NP_LIST  512
#define NP_WGT   (NP_LIST + SZ_LIST)
#define NP_MAP   (NP_WGT + SZ_WGT)
#define NP_WPR   (NP_MAP + SZ_MAP)
#define NP_XH    (NP_WPR + SZ_WPR)
#define NP_GU    (NP_XH + (size_t)NTOK*HIDDEN*2)
#define NP_C2    (NP_GU + (size_t)2*NTOK*(2*INTER)*2)
#define NP_END   (NP_C2 + (size_t)2*NTOK*HIDDEN*2)      // ~48.5 MB

// ---------------- Router ----------------------------------------------------
__global__ __launch_bounds__(256) void moe_router(
    const float* __restrict__ X, const float* __restrict__ Wr,
    f16* __restrict__ Xh, int* __restrict__ cnt,
    int* __restrict__ list, float* __restrict__ wgt,
    int4* __restrict__ map, float2* __restrict__ wpr)
{
  const int t = blockIdx.x, tid = threadIdx.x;
  const float* xrow = X + (size_t)t * HIDDEN;
  const int h0 = tid * 8;
  float4 xa = *(const float4*)(xrow + h0);
  float4 xb = *(const float4*)(xrow + h0 + 4);
  float xs[8] = {xa.x, xa.y, xa.z, xa.w, xb.x, xb.y, xb.z, xb.w};
  f16x8 xh;
#pragma unroll
  for (int j = 0; j < 8; ++j) xh[j] = (f16)xs[j];
  *(f16x8*)(Xh + (size_t)t * HIDDEN + h0) = xh;

  float acc[8] = {0.f,0.f,0.f,0.f,0.f,0.f,0.f,0.f};
#pragma unroll
  for (int j = 0; j < 8; ++j) {
    const float4* wr = (const float4*)(Wr + (size_t)(h0 + j) * NEXP);
    float4 wa = wr[0], wb = wr[1];
    acc[0] += xs[j]*wa.x; acc[1] += xs[j]*wa.y; acc[2] += xs[j]*wa.z; acc[3] += xs[j]*wa.w;
    acc[4] += xs[j]*wb.x; acc[5] += xs[j]*wb.y; acc[6] += xs[j]*wb.z; acc[7] += xs[j]*wb.w;
  }
  // wave-level butterfly reduce, then tiny cross-wave LDS combine
  const int lane = tid & 63, wid = tid >> 6;
#pragma unroll
  for (int e = 0; e < 8; ++e) {
#pragma unroll
    for (int s = 1; s < 64; s <<= 1) acc[e] += __shfl_xor(acc[e], s, 64);
  }
  __shared__ float red[4][8];
  if (lane == 0) {
#pragma unroll
    for (int e = 0; e < 8; ++e) red[wid][e] = acc[e];
  }
  __syncthreads();
  if (tid == 0) {
    float l[8];
#pragma unroll
    for (int e = 0; e < 8; ++e)
      l[e] = red[0][e] + red[1][e] + red[2][e] + red[3][e];
    int i1 = 0;
#pragma unroll
    for (int e = 1; e < 8; ++e) if (l[e] > l[i1]) i1 = e;
    int i2 = (i1 == 0) ? 1 : 0;
#pragma unroll
    for (int e = 0; e < 8; ++e) if (e != i1 && l[e] > l[i2]) i2 = e;
    float w1 = 1.f / (1.f + expf(l[i2] - l[i1]));
    float w2 = 1.f - w1;
    int p1 = atomicAdd(cnt + i1, 1);
    list[i1*NTOK + p1] = t; wgt[i1*NTOK + p1] = w1;
    int p2 = atomicAdd(cnt + i2, 1);
    list[i2*NTOK + p2] = t; wgt[i2*NTOK + p2] = w2;
    map[t] = make_int4(i1, p1, i2, p2);
    wpr[t] = make_float2(w1, w2);
  }
}

__global__ void moe_scan(const int* __restrict__ cnt, int* __restrict__ offs)
{
  if (threadIdx.x == 0 && blockIdx.x == 0) {
    int s = 0;
    for (int e = 0; e < NEXP; ++e) { offs[e] = s; s += cnt[e]; }
  }
}

// ---------------- GEMM1: GU[row][0:2816] = Xg @ [Wg|Wu] ---------------------
// B is reg-staged straight from fp32 weights, producing the SAME swizzled LDS
// image the old w_cvt_tile pass produced: slot s (=tid / tid+256) holds
// row ra = s>>2 (N-dim), source k-chunk kc = (s&3)^((ra>>1)&3), 8 f16 at
// Bs + s*8. The ds_read/MFMA side is unchanged.
__global__ __launch_bounds__(256, 4) void moe_gemm1_f16(
    const f16* __restrict__ Xh, const float* __restrict__ Wg,
    const float* __restrict__ Wu, f16* __restrict__ GU,
    const int* __restrict__ cnt, const int* __restrict__ offs,
    const int* __restrict__ list)
{
  const int e  = blockIdx.z;
  const int c  = cnt[e];
  const int m0 = blockIdx.y * 128;
  if (m0 >= c) return;
  const int n0  = blockIdx.x * 128;
  const int off = offs[e];
  const int tid = threadIdx.x;

  __shared__ f16 As[128*32];
  __shared__ f16 Bs[128*32];

  const int lane = tid & 63;
  const int w    = tid >> 6;
  const int lrow = lane & 15;
  const int q    = lane >> 4;
  const int mb   = (w & 1) * 64;
  const int nb   = (w >> 1) * 64;

  const int s0 = tid, s1 = tid + 256;
  const int ra0 = s0 >> 2, kc0 = (s0 & 3) ^ ((ra0 >> 1) & 3);
  const int ra1 = s1 >> 2, kc1 = (s1 & 3) ^ ((ra1 >> 1) & 3);
  f16* ldsA0 = As + (size_t)(w*64)*8;
  f16* ldsA1 = As + (size_t)(256 + w*64)*8;

  // token row base pointers in registers (no LDS indirection in the K-loop)
  const int tok0 = list[e*NTOK + min(m0 + ra0, c - 1)];
  const int tok1 = list[e*NTOK + min(m0 + ra1, c - 1)];
  const f16* pa0 = Xh + (size_t)tok0 * HIDDEN + kc0*8;
  const f16* pa1 = Xh + (size_t)tok1 * HIDDEN + kc1*8;

  // fp32 B source: gate for n0<INTER, up otherwise (per-thread strided rows)
  const float* Bsrc = (n0 < INTER) ? (Wg + (size_t)e * HIDDEN * INTER)
                                   : (Wu + (size_t)e * HIDDEN * INTER);
  const int nloc = (n0 < INTER) ? n0 : n0 - INTER;
  const float* pb0 = Bsrc + (size_t)(kc0 * 8) * INTER + (nloc + ra0);
  const float* pb1 = Bsrc + (size_t)(kc1 * 8) * INTER + (nloc + ra1);

  f32x4 acc[16];
#pragma unroll
  for (int i = 0; i < 16; ++i) acc[i] = (f32x4){0.f,0.f,0.f,0.f};

  for (int ks = 0; ks < HIDDEN/32; ++ks) {
    __syncthreads();
    gl_lds16(pa0 + ks*32, ldsA0);
    gl_lds16(pa1 + ks*32, ldsA1);
    {
      float v[8];
#pragma unroll
      for (int j = 0; j < 8; ++j) v[j] = pb0[(size_t)j * INTER];
      f16x8 hv;
#pragma unroll
      for (int j = 0; j < 4; ++j) {
        f16x2 pk = pkrtz(v[2*j], v[2*j+1]);
        hv[2*j] = pk[0]; hv[2*j+1] = pk[1];
      }
      *(f16x8*)(Bs + (size_t)s0 * 8) = hv;
    }
    {
      float v[8];
#pragma unroll
      for (int j = 0; j < 8; ++j) v[j] = pb1[(size_t)j * INTER];
      f16x8 hv;
#pragma unroll
      for (int j = 0; j < 4; ++j) {
        f16x2 pk = pkrtz(v[2*j], v[2*j+1]);
        hv[2*j] = pk[0]; hv[2*j+1] = pk[1];
      }
      *(f16x8*)(Bs + (size_t)s1 * 8) = hv;
    }
    pb0 += (size_t)32 * INTER;
    pb1 += (size_t)32 * INTER;
    __syncthreads();
    f16x8 af[4], bf[4];
#pragma unroll
    for (int tm = 0; tm < 4; ++tm) {
      int row = mb + tm*16 + lrow;
      int ch  = q ^ ((row >> 1) & 3);
      af[tm] = *(const f16x8*)(As + row*32 + ch*8);
    }
#pragma unroll
    for (int tn = 0; tn < 4; ++tn) {
      int row = nb + tn*16 + lrow;
      int ch  = q ^ ((row >> 1) & 3);
      bf[tn] = *(const f16x8*)(Bs + row*32 + ch*8);
    }
#pragma unroll
    for (int tm = 0; tm < 4; ++tm)
#pragma unroll
      for (int tn = 0; tn < 4; ++tn)
        acc[tm*4+tn] = __builtin_amdgcn_mfma_f32_16x16x32_f16(
            af[tm], bf[tn], acc[tm*4+tn], 0, 0, 0);
  }
#pragma unroll
  for (int tm = 0; tm < 4; ++tm)
#pragma unroll
    for (int tn = 0; tn < 4; ++tn)
#pragma unroll
      for (int j = 0; j < 4; ++j) {
        int lr = mb + tm*16 + q*4 + j;
        if (m0 + lr < c)
          GU[(size_t)(off + m0 + lr) * (2*INTER) + (n0 + nb + tn*16 + lrow)] =
              (f16)acc[tm*4+tn][j];
      }
}

// ---------------- SiLU-mul in place: GU[r][0:1408] = silu(g)*u --------------
__global__ __launch_bounds__(256) void moe_silu(f16* __restrict__ GU)
{
  const int r = blockIdx.x, t = threadIdx.x;
  if (t >= INTER/8) return;
  f16* row = GU + (size_t)r * (2*INTER);
  f16x8 g = *(f16x8*)(row + t*8);
  f16x8 u = *(f16x8*)(row + INTER + t*8);
  f16x8 h;
#pragma unroll
  for (int j = 0; j < 8; ++j) {
    float gf = (float)g[j];
    float s  = gf / (1.f + __expf(-gf));
    h[j] = (f16)(s * (float)u[j]);
  }
  *(f16x8*)(row + t*8) = h;
}

// ---------------- GEMM2: C2[row] = H @ Wd  (compact, unweighted) ------------
__global__ __launch_bounds__(256, 4) void moe_gemm2_f16(
    const f16* __restrict__ GU, const float* __restrict__ Wd,
    f16* __restrict__ C2,
    const int* __restrict__ cnt, const int* __restrict__ offs)
{
  const int e  = blockIdx.z;
  const int c  = cnt[e];
  const int m0 = blockIdx.y * 128;
  if (m0 >= c) return;
  const int n0  = blockIdx.x * 128;
  const int off = offs[e];
  const int tid = threadIdx.x;

  __shared__ f16 As[128*32];
  __shared__ f16 Bs[128*32];

  const int lane = tid & 63;
  const int w    = tid >> 6;
  const int lrow = lane & 15;
  const int q    = lane >> 4;
  const int mb   = (w & 1) * 64;
  const int nb   = (w >> 1) * 64;

  const int s0 = tid, s1 = tid + 256;
  const int ra0 = s0 >> 2, kc0 = (s0 & 3) ^ ((ra0 >> 1) & 3);
  const int ra1 = s1 >> 2, kc1 = (s1 & 3) ^ ((ra1 >> 1) & 3);
  f16* ldsA0 = As + (size_t)(w*64)*8;
  f16* ldsA1 = As + (size_t)(256 + w*64)*8;

  const f16* pa0 = GU + (size_t)(off + min(m0 + ra0, c - 1)) * (2*INTER) + kc0*8;
  const f16* pa1 = GU + (size_t)(off + min(m0 + ra1, c - 1)) * (2*INTER) + kc1*8;

  const float* Wde = Wd + (size_t)e * INTER * HIDDEN;
  const float* pb0 = Wde + (size_t)(kc0 * 8) * HIDDEN + (n0 + ra0);
  const float* pb1 = Wde + (size_t)(kc1 * 8) * HIDDEN + (n0 + ra1);

  f32x4 acc[16];
#pragma unroll
  for (int i = 0; i < 16; ++i) acc[i] = (f32x4){0.f,0.f,0.f,0.f};

  for (int ks = 0; ks < INTER/32; ++ks) {
    __syncthreads();
    gl_lds16(pa0 + ks*32, ldsA0);
    gl_lds16(pa1 + ks*32, ldsA1);
    {
      float v[8];
#pragma unroll
      for (int j = 0; j < 8; ++j) v[j] = pb0[(size_t)j * HIDDEN];
      f16x8 hv;
#pragma unroll
      for (int j = 0; j < 4; ++j) {
        f16x2 pk = pkrtz(v[2*j], v[2*j+1]);
        hv[2*j] = pk[0]; hv[2*j+1] = pk[1];
      }
      *(f16x8*)(Bs + (size_t)s0 * 8) = hv;
    }
    {
      float v[8];
#pragma unroll
      for (int j = 0; j < 8; ++j) v[j] = pb1[(size_t)j * HIDDEN];
      f16x8 hv;
#pragma unroll
      for (int j = 0; j < 4; ++j) {
        f16x2 pk = pkrtz(v[2*j], v[2*j+1]);
        hv[2*j] = pk[0]; hv[2*j+1] = pk[1];
      }
      *(f16x8*)(Bs + (size_t)s1 * 8) = hv;
    }
    pb0 += (size_t)32 * HIDDEN;
    pb1 += (size_t)32 * HIDDEN;
    __syncthreads();
    f16x8 af[4], bf[4];
#pragma unroll
    for (int tm = 0; tm < 4; ++tm) {
      int row = mb + tm*16 + lrow;
      int ch  = q ^ ((row >> 1) & 3);
      af[tm] = *(const f16x8*)(As + row*32 + ch*8);
    }
#pragma unroll
    for (int tn = 0; tn < 4; ++tn) {
      int row = nb + tn*16 + lrow;
      int ch  = q ^ ((row >> 1) & 3);
      bf[tn] = *(const f16x8*)(Bs + row*32 + ch*8);
    }
#pragma unroll
    for (int tm = 0; tm < 4; ++tm)
#pragma unroll
      for (int tn = 0; tn < 4; ++tn)
        acc[tm*4+tn] = __builtin_amdgcn_mfma_f32_16x16x32_f16(
            af[tm], bf[tn], acc[tm*4+tn], 0, 0, 0);
  }
#pragma unroll
  for (int tm = 0; tm < 4; ++tm)
#pragma unroll
    for (int tn = 0; tn < 4; ++tn)
#pragma unroll
      for (int j = 0; j < 4; ++j) {
        int lr = mb + tm*16 + q*4 + j;
        if (m0 + lr < c)
          C2[(size_t)(off + m0 + lr) * HIDDEN + (n0 + nb + tn*16 + lrow)] =
              (f16)acc[tm*4+tn][j];
      }
}

// ---------------- combine: out[t] = w1*C2[r1] + w2*C2[r2] -------------------
__global__ __launch_bounds__(256) void moe_combine(
    const f16* __restrict__ C2, const int4* __restrict__ map,
    const float2* __restrict__ wpr, const int* __restrict__ offs,
    float* __restrict__ out)
{
  const int t = blockIdx.x, tid = threadIdx.x;
  int4 m = map[t];
  float2 wv = wpr[t];
  const size_t r1 = (size_t)(offs[m.x] + m.y) * HIDDEN;
  const size_t r2 = (size_t)(offs[m.z] + m.w) * HIDDEN;
  f16x8 a = *(const f16x8*)(C2 + r1 + tid*8);
  f16x8 b = *(const f16x8*)(C2 + r2 + tid*8);
  float4 o0, o1;
  float* po = out + (size_t)t * HIDDEN + tid*8;
  o0.x = wv.x*(float)a[0] + wv.y*(float)b[0];
  o0.y = wv.x*(float)a[1] + wv.y*(float)b[1];
  o0.z = wv.x*(float)a[2] + wv.y*(float)b[2];
  o0.w = wv.x*(float)a[3] + wv.y*(float)b[3];
  o1.x = wv.x*(float)a[4] + wv.y*(float)b[4];
  o1.y = wv.x*(float)a[5] + wv.y*(float)b[5];
  o1.z = wv.x*(float)a[6] + wv.y*(float)b[6];
  o1.w = wv.x*(float)a[7] + wv.y*(float)b[7];
  *(float4*)po = o0;
  *(float4*)(po + 4) = o1;
}

// ================= fallback (round-2) GEMMs =================================
__global__ __launch_bounds__(256, 2) void moe_gemm1(
    const f16* __restrict__ Xh, const float* __restrict__ Wg,
    const float* __restrict__ Wu, f16* __restrict__ H,
    const int* __restrict__ cnt, const int* __restrict__ offs,
    const int* __restrict__ list)
{
  const int e  = blockIdx.z;
  const int c  = cnt[e];
  const int m0 = blockIdx.y * 128;
  if (m0 >= c) return;
  const int n0  = blockIdx.x * 128;
  const int off = offs[e];
  const int tid = threadIdx.x;

  __shared__ f16 As[128][40];
  __shared__ f16 Bs[128][40];
  __shared__ int tokLds[128];
  if (tid < 128) tokLds[tid] = list[e*NTOK + min(m0 + tid, c - 1)];

  const int lane = tid & 63;
  const int w    = tid >> 6;
  const int lrow = lane & 15;
  const int q    = lane >> 4;
  const int mb   = (w & 1) * 64;
  const int nb   = (w >> 1) * 64;
  const int ar = tid >> 1;
  const int ah = (tid & 1) * 16;
  const int bn = tid & 31;
  const int bk = (tid >> 5) * 4;

  const size_t ebase = (size_t)e * HIDDEN * INTER;
  const float* Wge = Wg + ebase;
  const float* Wue = Wu + ebase;

  f16x4 sg[16];
  f32x4 acc[16];

  for (int pass = 0; pass < 2; ++pass) {
    const float* B = pass ? Wue : Wge;
#pragma unroll
    for (int i = 0; i < 16; ++i) acc[i] = (f32x4){0.f, 0.f, 0.f, 0.f};
    for (int ks = 0; ks < HIDDEN/32; ++ks) {
      const int k0 = ks * 32;
      __syncthreads();
      {
        const uint4* src = (const uint4*)(Xh + (size_t)tokLds[ar] * HIDDEN + k0 + ah);
        uint4 a0 = src[0], a1 = src[1];
        uint2* dst = (uint2*)&As[ar][ah];
        dst[0] = make_uint2(a0.x, a0.y);
        dst[1] = make_uint2(a0.z, a0.w);
        dst[2] = make_uint2(a1.x, a1.y);
        dst[3] = make_uint2(a1.z, a1.w);
      }
#pragma unroll
      for (int g = 0; g < 4; ++g) {
        const int ncol = bn + 32*g;
        const float* bp = B + (size_t)(k0 + bk) * INTER + (n0 + ncol);
        float v0 = bp[0*INTER], v1 = bp[1*INTER], v2 = bp[2*INTER], v3 = bp[3*INTER];
        f16x2 p01 = pkrtz(v0, v1), p23 = pkrtz(v2, v3);
        f16x4 hv; hv[0] = p01[0]; hv[1] = p01[1]; hv[2] = p23[0]; hv[3] = p23[1];
        *(f16x4*)&Bs[ncol][bk] = hv;
      }
      __syncthreads();
      f16x8 af[4], bf[4];
#pragma unroll
      for (int tm = 0; tm < 4; ++tm) {
        const f16* p = &As[mb + tm*16 + lrow][q*8];
        f16x4 lo = *(const f16x4*)p, hi = *(const f16x4*)(p + 4);
        af[tm] = (f16x8){lo[0],lo[1],lo[2],lo[3],hi[0],hi[1],hi[2],hi[3]};
      }
#pragma unroll
      for (int tn = 0; tn < 4; ++tn) {
        const f16* p = &Bs[nb + tn*16 + lrow][q*8];
        f16x4 lo = *(const f16x4*)p, hi = *(const f16x4*)(p + 4);
        bf[tn] = (f16x8){lo[0],lo[1],lo[2],lo[3],hi[0],hi[1],hi[2],hi[3]};
      }
#pragma unroll
      for (int tm = 0; tm < 4; ++tm)
#pragma unroll
        for (int tn = 0; tn < 4; ++tn)
          acc[tm*4+tn] = __builtin_amdgcn_mfma_f32_16x16x32_f16(
              af[tm], bf[tn], acc[tm*4+tn], 0, 0, 0);
    }
    if (pass == 0) {
#pragma unroll
      for (int i = 0; i < 16; ++i)
#pragma unroll
        for (int j = 0; j < 4; ++j) {
          float g = acc[i][j];
          sg[i][j] = (f16)(g / (1.f + __expf(-g)));
        }
    }
  }
#pragma unroll
  for (int tm = 0; tm < 4; ++tm)
#pragma unroll
    for (int tn = 0; tn < 4; ++tn)
#pragma unroll
      for (int j = 0; j < 4; ++j) {
        int lr = mb + tm*16 + q*4 + j;
        if (m0 + lr < c) {
          float h = (float)sg[tm*4+tn][j] * acc[tm*4+tn][j];
          H[(size_t)(off + m0 + lr) * INTER + (n0 + nb + tn*16 + lrow)] = (f16)h;
        }
      }
}

__global__ __launch_bounds__(256, 2) void moe_gemm2(
    const f16* __restrict__ H, const float* __restrict__ Wd,
    float* __restrict__ out,
    const int* __restrict__ cnt, const int* __restrict__ offs,
    const int* __restrict__ list, const float* __restrict__ wgt)
{
  const int e  = blockIdx.z;
  const int c  = cnt[e];
  const int m0 = blockIdx.y * 128;
  if (m0 >= c) return;
  const int n0  = blockIdx.x * 128;
  const int off = offs[e];
  const int tid = threadIdx.x;

  __shared__ f16 As[128][40];
  __shared__ f16 Bs[128][40];
  __shared__ int   tokLds[128];
  __shared__ float wLds[128];
  if (tid < 128) {
    int s = e*NTOK + min(m0 + tid, c - 1);
    tokLds[tid] = list[s];
    wLds[tid]   = wgt[s];
  }
  const int lane = tid & 63;
  const int w    = tid >> 6;
  const int lrow = lane & 15;
  const int q    = lane >> 4;
  const int mb   = (w & 1) * 64;
  const int nb   = (w >> 1) * 64;
  const int ar = tid >> 1;
  const int ah = (tid & 1) * 16;
  const int bn = tid & 31;
  const int bk = (tid >> 5) * 4;

  const int arow = off + min(m0 + ar, c - 1);
  const float* Wde = Wd + (size_t)e * INTER * HIDDEN;

  f32x4 acc[16];
#pragma unroll
  for (int i = 0; i < 16; ++i) acc[i] = (f32x4){0.f, 0.f, 0.f, 0.f};

  for (int ks = 0; ks < INTER/32; ++ks) {
    const int k0 = ks * 32;
    __syncthreads();
    {
      const uint4* src = (const uint4*)(H + (size_t)arow * INTER + k0 + ah);
      uint4 a0 = src[0], a1 = src[1];
      uint2* dst = (uint2*)&As[ar][ah];
      dst[0] = make_uint2(a0.x, a0.y);
      dst[1] = make_uint2(a0.z, a0.w);
      dst[2] = make_uint2(a1.x, a1.y);
      dst[3] = make_uint2(a1.z, a1.w);
    }
#pragma unroll
    for (int g = 0; g < 4; ++g) {
      const int ncol = bn + 32*g;
      const float* bp = Wde + (size_t)(k0 + bk) * HIDDEN + (n0 + ncol);
      float v0 = bp[0*HIDDEN], v1 = bp[1*HIDDEN], v2 = bp[2*HIDDEN], v3 = bp[3*HIDDEN];
      f16x2 p01 = pkrtz(v0, v1), p23 = pkrtz(v2, v3);
      f16x4 hv; hv[0] = p01[0]; hv[1] = p01[1]; hv[2] = p23[0]; hv[3] = p23[1];
      *(f16x4*)&Bs[ncol][bk] = hv;
    }
    __syncthreads();
    f16x8 af[4], bf[4];
#pragma unroll
    for (int tm = 0; tm < 4; ++tm) {
      const f16* p = &As[mb + tm*16 + lrow][q*8];
      f16x4 lo = *(const f16x4*)p, hi = *(const f16x4*)(p + 4);
      af[tm] = (f16x8){lo[0],lo[1],lo[2],lo[3],hi[0],hi[1],hi[2],hi[3]};
    }
#pragma unroll
    for (int tn = 0; tn < 4; ++tn) {
      const f16* p = &Bs[nb + tn*16 + lrow][q*8];
      f16x4 lo = *(const f16x4*)p, hi = *(const f16x4*)(p + 4);
      bf[tn] = (f16x8){lo[0],lo[1],lo[2],lo[3],hi[0],hi[1],hi[2],hi[3]};
    }
#pragma unroll
    for (int tm = 0; tm < 4; ++tm)
#pragma unroll
      for (int tn = 0; tn < 4; ++tn)
        acc[tm*4+tn] = __builtin_amdgcn_mfma_f32_16x16x32_f16(
            af[tm], bf[tn], acc[tm*4+tn], 0, 0, 0);
  }
#pragma unroll
  for (int tm = 0; tm < 4; ++tm)
#pragma unroll
    for (int tn = 0; tn < 4; ++tn)
#pragma unroll
      for (int j = 0; j < 4; ++j) {
        int lr = mb + tm*16 + q*4 + j;
        if (m0 + lr < c) {
          float v = acc[tm*4+tn][j] * wLds[lr];
          atomicAdd(out + (size_t)tokLds[lr] * HIDDEN + (n0 + nb + tn*16 + lrow), v);
        }
      }
}

// ---------------- launch ----------------------------------------------------
extern "C" void kernel_launch(void* const* d_in, const int* in_sizes, int n_in,
                              void* d_out, int out_size, void* d_ws, size_t ws_size,
                              hipStream_t stream)
{
  const float* X  = (const float*)d_in[0];
  const float* Wr = (const float*)d_in[1];
  const float* Wg = (const float*)d_in[2];
  const float* Wu = (const float*)d_in[3];
  const float* Wd = (const float*)d_in[4];
  float* out = (float*)d_out;
  char* ws   = (char*)d_ws;

  if (ws_size >= (size_t)NP_END) {
    int*    cnt  = (int*)(ws + NP_CNT);
    int*    offs = (int*)(ws + NP_OFFS);
    int*    list = (int*)(ws + NP_LIST);
    float*  wgt  = (float*)(ws + NP_WGT);
    int4*   map  = (int4*)(ws + NP_MAP);
    float2* wpr  = (float2*)(ws + NP_WPR);
    f16*    Xh   = (f16*)(ws + NP_XH);
    f16*    GU   = (f16*)(ws + NP_GU);
    f16*    C2   = (f16*)(ws + NP_C2);

    (void)hipMemsetAsync(cnt, 0, NEXP * sizeof(int), stream);
    moe_router<<<NTOK, 256, 0, stream>>>(X, Wr, Xh, cnt, list, wgt, map, wpr);
    moe_scan<<<1, 64, 0, stream>>>(cnt, offs);
    moe_gemm1_f16<<<dim3(2*INTER/128, NTOK/128, NEXP), 256, 0, stream>>>(
        Xh, Wg, Wu, GU, cnt, offs, list);
    moe_silu<<<2*NTOK, 256, 0, stream>>>(GU);
    moe_gemm2_f16<<<dim3(HIDDEN/128, NTOK/128, NEXP), 256, 0, stream>>>(
        GU, Wd, C2, cnt, offs);
    moe_combine<<<NTOK, 256, 0, stream>>>(C2, map, wpr, offs, out);
  } else {
    int*   cnt  = (int*)(ws + OP_CNT);
    int*   offs = (int*)(ws + OP_OFFS);
    int*   list = (int*)(ws + OP_LIST);
    float* wgt  = (float*)(ws + OP_WGT);
    int4*  map  = (int4*)(ws + OP_MAP);
    float2* wpr = (float2*)(ws + OP_WPR);
    f16*   Xh   = (f16*)(ws + OP_XH);
    f16*   H    = (f16*)(ws + OP_H);

    (void)hipMemsetAsync(cnt, 0, NEXP * sizeof(int), stream);
    (void)hipMemsetAsync(out, 0, (size_t)NTOK * HIDDEN * sizeof(float), stream);
    moe_router<<<NTOK, 256, 0, stream>>>(X, Wr, Xh, cnt, list, wgt, map, wpr);
    moe_scan<<<1, 64, 0, stream>>>(cnt, offs);
    moe_gemm1<<<dim3(INTER/128, NTOK/128, NEXP), 256, 0, stream>>>(
        Xh, Wg, Wu, H, cnt, offs, list);
    moe_gemm2<<<dim3(HIDDEN/128, NTOK/128, NEXP), 256, 0, stream>>>(
        H, Wd, out, cnt, offs, list, wgt);
  }
}

// Round 2
// 537.177 us; speedup vs baseline: 1.1857x; 1.1857x over previous
//
#include <hip/hip_runtime.h>
#include <hip/hip_fp16.h>

#define HIDDEN 2048
#define INTER  1408
#define NEXP   8
#define NTOK   2048

typedef _Float16 f16;
typedef _Float16 f16x2 __attribute__((ext_vector_type(2)));
typedef _Float16 f16x4 __attribute__((ext_vector_type(4)));
typedef _Float16 f16x8 __attribute__((ext_vector_type(8)));
typedef float f32x4 __attribute__((ext_vector_type(4)));

static __device__ __forceinline__ f16x2 pkrtz(float a, float b) {
  return __builtin_bit_cast(f16x2, __builtin_amdgcn_cvt_pkrtz(a, b));
}

// async 16B global -> LDS. Dest = wave-uniform base + lane*16 (HW rule).
static __device__ __forceinline__ void gl_lds16(const f16* g, f16* l) {
  __builtin_amdgcn_global_load_lds(
      (const __attribute__((address_space(1))) void*)g,
      (__attribute__((address_space(3))) void*)l, 16, 0, 0);
}

// ---------------- workspace layouts ----------------------------------------
#define SZ_LIST (NEXP*NTOK*4)
#define SZ_WGT  (NEXP*NTOK*4)
#define SZ_MAP  (NTOK*16)
#define SZ_WPR  (NTOK*8)
// fallback path
#define OP_CNT   0
#define OP_OFFS  256
#define OP_LIST  512
#define OP_WGT   (OP_LIST + SZ_LIST)
#define OP_MAP   (OP_WGT + SZ_WGT)
#define OP_WPR   (OP_MAP + SZ_MAP)
#define OP_XH    (OP_WPR + SZ_WPR)
#define OP_H     (OP_XH + (size_t)NTOK*HIDDEN*2)
#define OP_END   (OP_H + (size_t)2*NTOK*INTER*2)
// fast path: tiled f16 weights + compact H
#define NP_CNT   0
#define NP_OFFS  256
#define NP_LIST  512
#define NP_WGT   (NP_LIST + SZ_LIST)
#define NP_MAP   (NP_WGT + SZ_WGT)
#define NP_WPR   (NP_MAP + SZ_MAP)
#define NP_XH    (NP_WPR + SZ_WPR)
#define NP_WGU   (NP_XH + (size_t)NTOK*HIDDEN*2)
#define NP_WDT   (NP_WGU + (size_t)NEXP*2*INTER*HIDDEN*2)
#define NP_H     (NP_WDT + (size_t)NEXP*HIDDEN*INTER*2)
#define NP_C2    (NP_H + (size_t)2*NTOK*INTER*2)
#define NP_END   (NP_C2 + (size_t)2*NTOK*HIDDEN*2)      // ~175 MB

// ---------------- Router ----------------------------------------------------
__global__ __launch_bounds__(256) void moe_router(
    const float* __restrict__ X, const float* __restrict__ Wr,
    f16* __restrict__ Xh, int* __restrict__ cnt,
    int* __restrict__ list, float* __restrict__ wgt,
    int4* __restrict__ map, float2* __restrict__ wpr)
{
  const int t = blockIdx.x, tid = threadIdx.x;
  const float* xrow = X + (size_t)t * HIDDEN;
  const int h0 = tid * 8;
  float4 xa = *(const float4*)(xrow + h0);
  float4 xb = *(const float4*)(xrow + h0 + 4);
  float xs[8] = {xa.x, xa.y, xa.z, xa.w, xb.x, xb.y, xb.z, xb.w};
  f16x8 xh;
#pragma unroll
  for (int j = 0; j < 8; ++j) xh[j] = (f16)xs[j];
  *(f16x8*)(Xh + (size_t)t * HIDDEN + h0) = xh;

  float acc[8] = {0.f,0.f,0.f,0.f,0.f,0.f,0.f,0.f};
#pragma unroll
  for (int j = 0; j < 8; ++j) {
    const float4* wr = (const float4*)(Wr + (size_t)(h0 + j) * NEXP);
    float4 wa = wr[0], wb = wr[1];
    acc[0] += xs[j]*wa.x; acc[1] += xs[j]*wa.y; acc[2] += xs[j]*wa.z; acc[3] += xs[j]*wa.w;
    acc[4] += xs[j]*wb.x; acc[5] += xs[j]*wb.y; acc[6] += xs[j]*wb.z; acc[7] += xs[j]*wb.w;
  }
  const int lane = tid & 63, wid = tid >> 6;
#pragma unroll
  for (int e = 0; e < 8; ++e) {
#pragma unroll
    for (int s = 1; s < 64; s <<= 1) acc[e] += __shfl_xor(acc[e], s, 64);
  }
  __shared__ float red[4][8];
  if (lane == 0) {
#pragma unroll
    for (int e = 0; e < 8; ++e) red[wid][e] = acc[e];
  }
  __syncthreads();
  if (tid == 0) {
    float l[8];
#pragma unroll
    for (int e = 0; e < 8; ++e)
      l[e] = red[0][e] + red[1][e] + red[2][e] + red[3][e];
    int i1 = 0;
#pragma unroll
    for (int e = 1; e < 8; ++e) if (l[e] > l[i1]) i1 = e;
    int i2 = (i1 == 0) ? 1 : 0;
#pragma unroll
    for (int e = 0; e < 8; ++e) if (e != i1 && l[e] > l[i2]) i2 = e;
    float w1 = 1.f / (1.f + expf(l[i2] - l[i1]));
    float w2 = 1.f - w1;
    int p1 = atomicAdd(cnt + i1, 1);
    list[i1*NTOK + p1] = t; wgt[i1*NTOK + p1] = w1;
    int p2 = atomicAdd(cnt + i2, 1);
    list[i2*NTOK + p2] = t; wgt[i2*NTOK + p2] = w2;
    map[t] = make_int4(i1, p1, i2, p2);
    wpr[t] = make_float2(w1, w2);
  }
}

__global__ void moe_scan(const int* __restrict__ cnt, int* __restrict__ offs)
{
  if (threadIdx.x == 0 && blockIdx.x == 0) {
    int s = 0;
    for (int e = 0; e < NEXP; ++e) { offs[e] = s; s += cnt[e]; }
  }
}

// -------- fp32 [E][K][N] -> tiled f16 [e][nb][ks][512 slots x 8 f16] --------
// Coalesced rewrite: float4 global reads -> LDS fp32 tile -> transposed
// f16x8 writes. Output image identical to the original gather version:
// slot s holds col ra = s>>2, k-chunk kc = (s&3)^((ra>>1)&3).
__global__ __launch_bounds__(256) void w_cvt_tile(
    const float* __restrict__ src, f16* __restrict__ dst,
    int K, int N, int nbOfs, int nbTot)
{
  const int ksTot = K >> 5;
  const int e  = blockIdx.y;
  const int nb = blockIdx.x / ksTot;
  const int ks = blockIdx.x - nb * ksTot;
  const int n0 = nb * 128, k0 = ks * 32;
  const float* s = src + (size_t)e * K * N + (size_t)k0 * N + n0;
  f16* d = dst + (((size_t)e * nbTot + nbOfs + nb) * ksTot + ks) * 4096;
  const int t = threadIdx.x;
  __shared__ float lt[32][132];   // 132-float row stride keeps 16B alignment
#pragma unroll
  for (int p = 0; p < 4; ++p) {
    const int idx = p * 256 + t;      // float4 index within the 32x128 tile
    const int row = idx >> 5;         // 32 float4 per row
    const int c4  = idx & 31;
    float4 v = *(const float4*)(s + (size_t)row * N + c4 * 4);
    *(float4*)&lt[row][c4 * 4] = v;
  }
  __syncthreads();
#pragma unroll
  for (int half = 0; half < 2; ++half) {
    const int slot = t + half * 256;
    const int ra = slot >> 2;
    const int kc = (slot & 3) ^ ((ra >> 1) & 3);
    f16x8 hv;
#pragma unroll
    for (int j = 0; j < 4; ++j) {
      f16x2 pk = pkrtz(lt[kc*8 + 2*j][ra], lt[kc*8 + 2*j + 1][ra]);
      hv[2*j] = pk[0]; hv[2*j+1] = pk[1];
    }
    *(f16x8*)(d + (size_t)slot * 8) = hv;
  }
}

// ---- GEMM1 (fused gate+up+silu): H[row][0:1408] = silu(X@Wg)*(X@Wu) --------
// BM=64 (more active blocks), 2x2 waves, per wave 32x64 of BOTH gate and up.
__global__ __launch_bounds__(256, 3) void moe_gemm1_f16(
    const f16* __restrict__ Xh, const f16* __restrict__ Wgu,
    f16* __restrict__ H,
    const int* __restrict__ cnt, const int* __restrict__ offs,
    const int* __restrict__ list)
{
  const int e  = blockIdx.z;
  const int c  = cnt[e];
  const int m0 = blockIdx.y * 64;
  if (m0 >= c) return;
  const int bx  = blockIdx.x;
  const int n0  = bx * 128;
  const int off = offs[e];
  const int tid = threadIdx.x;

  __shared__ f16 As[64*32];
  __shared__ f16 Bg[128*32];
  __shared__ f16 Bu[128*32];

  const int lane = tid & 63;
  const int w    = tid >> 6;
  const int lrow = lane & 15;
  const int q    = lane >> 4;
  const int wm   = (w & 1) * 32;
  const int wn   = (w >> 1) * 64;

  // A staging: 256 slots cover 64 rows x 32 k
  const int raA = tid >> 2, kcA = (tid & 3) ^ ((raA >> 1) & 3);
  const int tokA = list[e*NTOK + min(m0 + raA, c - 1)];
  const f16* pa = Xh + (size_t)tokA * HIDDEN + kcA*8;
  f16* ldsA = As + (size_t)(w*64)*8;

  // B staging: 512 slots per matrix
  const int s0 = tid, s1 = tid + 256;
  f16* ldsG0 = Bg + (size_t)(w*64)*8;
  f16* ldsG1 = Bg + (size_t)(256 + w*64)*8;
  f16* ldsU0 = Bu + (size_t)(w*64)*8;
  f16* ldsU1 = Bu + (size_t)(256 + w*64)*8;
  const f16* Btg = Wgu + ((size_t)(e*22 + bx)      * (HIDDEN/32)) * 4096;
  const f16* Btu = Wgu + ((size_t)(e*22 + 11 + bx) * (HIDDEN/32)) * 4096;

  f32x4 ag[8], au[8];
#pragma unroll
  for (int i = 0; i < 8; ++i) { ag[i] = (f32x4){0.f,0.f,0.f,0.f}; au[i] = ag[i]; }

  for (int ks = 0; ks < HIDDEN/32; ++ks) {
    __syncthreads();
    gl_lds16(pa + ks*32, ldsA);
    gl_lds16(Btg + (size_t)s0*8, ldsG0);
    gl_lds16(Btg + (size_t)s1*8, ldsG1);
    gl_lds16(Btu + (size_t)s0*8, ldsU0);
    gl_lds16(Btu + (size_t)s1*8, ldsU1);
    Btg += 4096; Btu += 4096;
    __syncthreads();
    f16x8 af[2], gf[4], uf[4];
#pragma unroll
    for (int tm = 0; tm < 2; ++tm) {
      int row = wm + tm*16 + lrow;
      int ch  = q ^ ((row >> 1) & 3);
      af[tm] = *(const f16x8*)(As + row*32 + ch*8);
    }
#pragma unroll
    for (int tn = 0; tn < 4; ++tn) {
      int row = wn + tn*16 + lrow;
      int ch  = q ^ ((row >> 1) & 3);
      gf[tn] = *(const f16x8*)(Bg + row*32 + ch*8);
      uf[tn] = *(const f16x8*)(Bu + row*32 + ch*8);
    }
#pragma unroll
    for (int tm = 0; tm < 2; ++tm)
#pragma unroll
      for (int tn = 0; tn < 4; ++tn) {
        ag[tm*4+tn] = __builtin_amdgcn_mfma_f32_16x16x32_f16(
            af[tm], gf[tn], ag[tm*4+tn], 0, 0, 0);
        au[tm*4+tn] = __builtin_amdgcn_mfma_f32_16x16x32_f16(
            af[tm], uf[tn], au[tm*4+tn], 0, 0, 0);
      }
  }
#pragma unroll
  for (int tm = 0; tm < 2; ++tm)
#pragma unroll
    for (int tn = 0; tn < 4; ++tn)
#pragma unroll
      for (int j = 0; j < 4; ++j) {
        int lr = wm + tm*16 + q*4 + j;
        if (m0 + lr < c) {
          float g = ag[tm*4+tn][j];
          float sgl = g / (1.f + __expf(-g));
          H[(size_t)(off + m0 + lr) * INTER + (n0 + wn + tn*16 + lrow)] =
              (f16)(sgl * au[tm*4+tn][j]);
        }
      }
}

// ---------------- GEMM2: C2[row] = H @ Wd  (compact, unweighted) ------------
__global__ __launch_bounds__(256, 4) void moe_gemm2_f16(
    const f16* __restrict__ H, const f16* __restrict__ Wdt,
    f16* __restrict__ C2,
    const int* __restrict__ cnt, const int* __restrict__ offs)
{
  const int e  = blockIdx.z;
  const int c  = cnt[e];
  const int m0 = blockIdx.y * 64;
  if (m0 >= c) return;
  const int bx  = blockIdx.x;
  const int n0  = bx * 128;
  const int off = offs[e];
  const int tid = threadIdx.x;

  __shared__ f16 As[64*32];
  __shared__ f16 Bs[128*32];

  const int lane = tid & 63;
  const int w    = tid >> 6;
  const int lrow = lane & 15;
  const int q    = lane >> 4;
  const int wm   = (w & 1) * 32;
  const int wn   = (w >> 1) * 64;

  const int raA = tid >> 2, kcA = (tid & 3) ^ ((raA >> 1) & 3);
  const f16* pa = H + (size_t)(off + min(m0 + raA, c - 1)) * INTER + kcA*8;
  f16* ldsA = As + (size_t)(w*64)*8;

  const int s0 = tid, s1 = tid + 256;
  f16* ldsB0 = Bs + (size_t)(w*64)*8;
  f16* ldsB1 = Bs + (size_t)(256 + w*64)*8;
  const f16* Bt = Wdt + ((size_t)(e*16 + bx) * (INTER/32)) * 4096;

  f32x4 acc[8];
#pragma unroll
  for (int i = 0; i < 8; ++i) acc[i] = (f32x4){0.f,0.f,0.f,0.f};

  for (int ks = 0; ks < INTER/32; ++ks) {
    __syncthreads();
    gl_lds16(pa + ks*32, ldsA);
    gl_lds16(Bt + (size_t)s0*8, ldsB0);
    gl_lds16(Bt + (size_t)s1*8, ldsB1);
    Bt += 4096;
    __syncthreads();
    f16x8 af[2], bf[4];
#pragma unroll
    for (int tm = 0; tm < 2; ++tm) {
      int row = wm + tm*16 + lrow;
      int ch  = q ^ ((row >> 1) & 3);
      af[tm] = *(const f16x8*)(As + row*32 + ch*8);
    }
#pragma unroll
    for (int tn = 0; tn < 4; ++tn) {
      int row = wn + tn*16 + lrow;
      int ch  = q ^ ((row >> 1) & 3);
      bf[tn] = *(const f16x8*)(Bs + row*32 + ch*8);
    }
#pragma unroll
    for (int tm = 0; tm < 2; ++tm)
#pragma unroll
      for (int tn = 0; tn < 4; ++tn)
        acc[tm*4+tn] = __builtin_amdgcn_mfma_f32_16x16x32_f16(
            af[tm], bf[tn], acc[tm*4+tn], 0, 0, 0);
  }
#pragma unroll
  for (int tm = 0; tm < 2; ++tm)
#pragma unroll
    for (int tn = 0; tn < 4; ++tn)
#pragma unroll
      for (int j = 0; j < 4; ++j) {
        int lr = wm + tm*16 + q*4 + j;
        if (m0 + lr < c)
          C2[(size_t)(off + m0 + lr) * HIDDEN + (n0 + wn + tn*16 + lrow)] =
              (f16)acc[tm*4+tn][j];
      }
}

// ---------------- combine: out[t] = w1*C2[r1] + w2*C2[r2] -------------------
__global__ __launch_bounds__(256) void moe_combine(
    const f16* __restrict__ C2, const int4* __restrict__ map,
    const float2* __restrict__ wpr, const int* __restrict__ offs,
    float* __restrict__ out)
{
  const int t = blockIdx.x, tid = threadIdx.x;
  int4 m = map[t];
  float2 wv = wpr[t];
  const size_t r1 = (size_t)(offs[m.x] + m.y) * HIDDEN;
  const size_t r2 = (size_t)(offs[m.z] + m.w) * HIDDEN;
  f16x8 a = *(const f16x8*)(C2 + r1 + tid*8);
  f16x8 b = *(const f16x8*)(C2 + r2 + tid*8);
  float4 o0, o1;
  float* po = out + (size_t)t * HIDDEN + tid*8;
  o0.x = wv.x*(float)a[0] + wv.y*(float)b[0];
  o0.y = wv.x*(float)a[1] + wv.y*(float)b[1];
  o0.z = wv.x*(float)a[2] + wv.y*(float)b[2];
  o0.w = wv.x*(float)a[3] + wv.y*(float)b[3];
  o1.x = wv.x*(float)a[4] + wv.y*(float)b[4];
  o1.y = wv.x*(float)a[5] + wv.y*(float)b[5];
  o1.z = wv.x*(float)a[6] + wv.y*(float)b[6];
  o1.w = wv.x*(float)a[7] + wv.y*(float)b[7];
  *(float4*)po = o0;
  *(float4*)(po + 4) = o1;
}

// ================= fallback (round-2) GEMMs =================================
__global__ __launch_bounds__(256, 2) void moe_gemm1(
    const f16* __restrict__ Xh, const float* __restrict__ Wg,
    const float* __restrict__ Wu, f16* __restrict__ H,
    const int* __restrict__ cnt, const int* __restrict__ offs,
    const int* __restrict__ list)
{
  const int e  = blockIdx.z;
  const int c  = cnt[e];
  const int m0 = blockIdx.y * 128;
  if (m0 >= c) return;
  const int n0  = blockIdx.x * 128;
  const int off = offs[e];
  const int tid = threadIdx.x;

  __shared__ f16 As[128][40];
  __shared__ f16 Bs[128][40];
  __shared__ int tokLds[128];
  if (tid < 128) tokLds[tid] = list[e*NTOK + min(m0 + tid, c - 1)];

  const int lane = tid & 63;
  const int w    = tid >> 6;
  const int lrow = lane & 15;
  const int q    = lane >> 4;
  const int mb   = (w & 1) * 64;
  const int nb   = (w >> 1) * 64;
  const int ar = tid >> 1;
  const int ah = (tid & 1) * 16;
  const int bn = tid & 31;
  const int bk = (tid >> 5) * 4;

  const size_t ebase = (size_t)e * HIDDEN * INTER;
  const float* Wge = Wg + ebase;
  const float* Wue = Wu + ebase;

  f16x4 sg[16];
  f32x4 acc[16];

  for (int pass = 0; pass < 2; ++pass) {
    const float* B = pass ? Wue : Wge;
#pragma unroll
    for (int i = 0; i < 16; ++i) acc[i] = (f32x4){0.f, 0.f, 0.f, 0.f};
    for (int ks = 0; ks < HIDDEN/32; ++ks) {
      const int k0 = ks * 32;
      __syncthreads();
      {
        const uint4* src = (const uint4*)(Xh + (size_t)tokLds[ar] * HIDDEN + k0 + ah);
        uint4 a0 = src[0], a1 = src[1];
        uint2* dst = (uint2*)&As[ar][ah];
        dst[0] = make_uint2(a0.x, a0.y);
        dst[1] = make_uint2(a0.z, a0.w);
        dst[2] = make_uint2(a1.x, a1.y);
        dst[3] = make_uint2(a1.z, a1.w);
      }
#pragma unroll
      for (int g = 0; g < 4; ++g) {
        const int ncol = bn + 32*g;
        const float* bp = B + (size_t)(k0 + bk) * INTER + (n0 + ncol);
        float v0 = bp[0*INTER], v1 = bp[1*INTER], v2 = bp[2*INTER], v3 = bp[3*INTER];
        f16x2 p01 = pkrtz(v0, v1), p23 = pkrtz(v2, v3);
        f16x4 hv; hv[0] = p01[0]; hv[1] = p01[1]; hv[2] = p23[0]; hv[3] = p23[1];
        *(f16x4*)&Bs[ncol][bk] = hv;
      }
      __syncthreads();
      f16x8 af[4], bf[4];
#pragma unroll
      for (int tm = 0; tm < 4; ++tm) {
        const f16* p = &As[mb + tm*16 + lrow][q*8];
        f16x4 lo = *(const f16x4*)p, hi = *(const f16x4*)(p + 4);
        af[tm] = (f16x8){lo[0],lo[1],lo[2],lo[3],hi[0],hi[1],hi[2],hi[3]};
      }
#pragma unroll
      for (int tn = 0; tn < 4; ++tn) {
        const f16* p = &Bs[nb + tn*16 + lrow][q*8];
        f16x4 lo = *(const f16x4*)p, hi = *(const f16x4*)(p + 4);
        bf[tn] = (f16x8){lo[0],lo[1],lo[2],lo[3],hi[0],hi[1],hi[2],hi[3]};
      }
#pragma unroll
      for (int tm = 0; tm < 4; ++tm)
#pragma unroll
        for (int tn = 0; tn < 4; ++tn)
          acc[tm*4+tn] = __builtin_amdgcn_mfma_f32_16x16x32_f16(
              af[tm], bf[tn], acc[tm*4+tn], 0, 0, 0);
    }
    if (pass == 0) {
#pragma unroll
      for (int i = 0; i < 16; ++i)
#pragma unroll
        for (int j = 0; j < 4; ++j) {
          float g = acc[i][j];
          sg[i][j] = (f16)(g / (1.f + __expf(-g)));
        }
    }
  }
#pragma unroll
  for (int tm = 0; tm < 4; ++tm)
#pragma unroll
    for (int tn = 0; tn < 4; ++tn)
#pragma unroll
      for (int j = 0; j < 4; ++j) {
        int lr = mb + tm*16 + q*4 + j;
        if (m0 + lr < c) {
          float h = (float)sg[tm*4+tn][j] * acc[tm*4+tn][j];
          H[(size_t)(off + m0 + lr) * INTER + (n0 + nb + tn*16 + lrow)] = (f16)h;
        }
      }
}

__global__ __launch_bounds__(256, 2) void moe_gemm2(
    const f16* __restrict__ H, const float* __restrict__ Wd,
    float* __restrict__ out,
    const int* __restrict__ cnt, const int* __restrict__ offs,
    const int* __restrict__ list, const float* __restrict__ wgt)
{
  const int e  = blockIdx.z;
  const int c  = cnt[e];
  const int m0 = blockIdx.y * 128;
  if (m0 >= c) return;
  const int n0  = blockIdx.x * 128;
  const int off = offs[e];
  const int tid = threadIdx.x;

  __shared__ f16 As[128][40];
  __shared__ f16 Bs[128][40];
  __shared__ int   tokLds[128];
  __shared__ float wLds[128];
  if (tid < 128) {
    int s = e*NTOK + min(m0 + tid, c - 1);
    tokLds[tid] = list[s];
    wLds[tid]   = wgt[s];
  }
  const int lane = tid & 63;
  const int w    = tid >> 6;
  const int lrow = lane & 15;
  const int q    = lane >> 4;
  const int mb   = (w & 1) * 64;
  const int nb   = (w >> 1) * 64;
  const int ar = tid >> 1;
  const int ah = (tid & 1) * 16;
  const int bn = tid & 31;
  const int bk = (tid >> 5) * 4;

  const int arow = off + min(m0 + ar, c - 1);
  const float* Wde = Wd + (size_t)e * INTER * HIDDEN;

  f32x4 acc[16];
#pragma unroll
  for (int i = 0; i < 16; ++i) acc[i] = (f32x4){0.f, 0.f, 0.f, 0.f};

  for (int ks = 0; ks < INTER/32; ++ks) {
    const int k0 = ks * 32;
    __syncthreads();
    {
      const uint4* src = (const uint4*)(H + (size_t)arow * INTER + k0 + ah);
      uint4 a0 = src[0], a1 = src[1];
      uint2* dst = (uint2*)&As[ar][ah];
      dst[0] = make_uint2(a0.x, a0.y);
      dst[1] = make_uint2(a0.z, a0.w);
      dst[2] = make_uint2(a1.x, a1.y);
      dst[3] = make_uint2(a1.z, a1.w);
    }
#pragma unroll
    for (int g = 0; g < 4; ++g) {
      const int ncol = bn + 32*g;
      const float* bp = Wde + (size_t)(k0 + bk) * HIDDEN + (n0 + ncol);
      float v0 = bp[0*HIDDEN], v1 = bp[1*HIDDEN], v2 = bp[2*HIDDEN], v3 = bp[3*HIDDEN];
      f16x2 p01 = pkrtz(v0, v1), p23 = pkrtz(v2, v3);
      f16x4 hv; hv[0] = p01[0]; hv[1] = p01[1]; hv[2] = p23[0]; hv[3] = p23[1];
      *(f16x4*)&Bs[ncol][bk] = hv;
    }
    __syncthreads();
    f16x8 af[4], bf[4];
#pragma unroll
    for (int tm = 0; tm < 4; ++tm) {
      const f16* p = &As[mb + tm*16 + lrow][q*8];
      f16x4 lo = *(const f16x4*)p, hi = *(const f16x4*)(p + 4);
      af[tm] = (f16x8){lo[0],lo[1],lo[2],lo[3],hi[0],hi[1],hi[2],hi[3]};
    }
#pragma unroll
    for (int tn = 0; tn < 4; ++tn) {
      const f16* p = &Bs[nb + tn*16 + lrow][q*8];
      f16x4 lo = *(const f16x4*)p, hi = *(const f16x4*)(p + 4);
      bf[tn] = (f16x8){lo[0],lo[1],lo[2],lo[3],hi[0],hi[1],hi[2],hi[3]};
    }
#pragma unroll
    for (int tm = 0; tm < 4; ++tm)
#pragma unroll
      for (int tn = 0; tn < 4; ++tn)
        acc[tm*4+tn] = __builtin_amdgcn_mfma_f32_16x16x32_f16(
            af[tm], bf[tn], acc[tm*4+tn], 0, 0, 0);
  }
#pragma unroll
  for (int tm = 0; tm < 4; ++tm)
#pragma unroll
    for (int tn = 0; tn < 4; ++tn)
#pragma unroll
      for (int j = 0; j < 4; ++j) {
        int lr = mb + tm*16 + q*4 + j;
        if (m0 + lr < c) {
          float v = acc[tm*4+tn][j] * wLds[lr];
          atomicAdd(out + (size_t)tokLds[lr] * HIDDEN + (n0 + nb + tn*16 + lrow), v);
        }
      }
}

// ---------------- launch ----------------------------------------------------
extern "C" void kernel_launch(void* const* d_in, const int* in_sizes, int n_in,
                              void* d_out, int out_size, void* d_ws, size_t ws_size,
                              hipStream_t stream)
{
  const float* X  = (const float*)d_in[0];
  const float* Wr = (const float*)d_in[1];
  const float* Wg = (const float*)d_in[2];
  const float* Wu = (const float*)d_in[3];
  const float* Wd = (const float*)d_in[4];
  float* out = (float*)d_out;
  char* ws   = (char*)d_ws;

  if (ws_size >= (size_t)NP_END) {
    int*    cnt  = (int*)(ws + NP_CNT);
    int*    offs = (int*)(ws + NP_OFFS);
    int*    list = (int*)(ws + NP_LIST);
    float*  wgt  = (float*)(ws + NP_WGT);
    int4*   map  = (int4*)(ws + NP_MAP);
    float2* wpr  = (float2*)(ws + NP_WPR);
    f16*    Xh   = (f16*)(ws + NP_XH);
    f16*    Wgu  = (f16*)(ws + NP_WGU);
    f16*    Wdt  = (f16*)(ws + NP_WDT);
    f16*    H    = (f16*)(ws + NP_H);
    f16*    C2   = (f16*)(ws + NP_C2);

    (void)hipMemsetAsync(cnt, 0, NEXP * sizeof(int), stream);
    moe_router<<<NTOK, 256, 0, stream>>>(X, Wr, Xh, cnt, list, wgt, map, wpr);
    moe_scan<<<1, 64, 0, stream>>>(cnt, offs);
    // gate -> Wgu nblk 0..10, up -> nblk 11..21, down -> Wdt nblk 0..15
    w_cvt_tile<<<dim3(11 * (HIDDEN/32), NEXP), 256, 0, stream>>>(
        Wg, Wgu, HIDDEN, INTER, 0, 22);
    w_cvt_tile<<<dim3(11 * (HIDDEN/32), NEXP), 256, 0, stream>>>(
        Wu, Wgu, HIDDEN, INTER, 11, 22);
    w_cvt_tile<<<dim3(16 * (INTER/32), NEXP), 256, 0, stream>>>(
        Wd, Wdt, INTER, HIDDEN, 0, 16);
    moe_gemm1_f16<<<dim3(INTER/128, NTOK/64, NEXP), 256, 0, stream>>>(
        Xh, Wgu, H, cnt, offs, list);
    moe_gemm2_f16<<<dim3(HIDDEN/128, NTOK/64, NEXP), 256, 0, stream>>>(
        H, Wdt, C2, cnt, offs);
    moe_combine<<<NTOK, 256, 0, stream>>>(C2, map, wpr, offs, out);
  } else {
    int*   cnt  = (int*)(ws + OP_CNT);
    int*   offs = (int*)(ws + OP_OFFS);
    int*   list = (int*)(ws + OP_LIST);
    float* wgt  = (float*)(ws + OP_WGT);
    int4*  map  = (int4*)(ws + OP_MAP);
    float2* wpr = (float2*)(ws + OP_WPR);
    f16*   Xh   = (f16*)(ws + OP_XH);
    f16*   H    = (f16*)(ws + OP_H);

    (void)hipMemsetAsync(cnt, 0, NEXP * sizeof(int), stream);
    (void)hipMemsetAsync(out, 0, (size_t)NTOK * HIDDEN * sizeof(float), stream);
    moe_router<<<NTOK, 256, 0, stream>>>(X, Wr, Xh, cnt, list, wgt, map, wpr);
    moe_scan<<<1, 64, 0, stream>>>(cnt, offs);
    moe_gemm1<<<dim3(INTER/128, NTOK/128, NEXP), 256, 0, stream>>>(
        Xh, Wg, Wu, H, cnt, offs, list);
    moe_gemm2<<<dim3(HIDDEN/128, NTOK/128, NEXP), 256, 0, stream>>>(
        H, Wd, out, cnt, offs, list, wgt);
  }
}

// Round 3
// 492.460 us; speedup vs baseline: 1.2933x; 1.0908x over previous
//
#include <hip/hip_runtime.h>
#include <hip/hip_fp16.h>

#define HIDDEN 2048
#define INTER  1408
#define NEXP   8
#define NTOK   2048

typedef _Float16 f16;
typedef _Float16 f16x2 __attribute__((ext_vector_type(2)));
typedef _Float16 f16x4 __attribute__((ext_vector_type(4)));
typedef _Float16 f16x8 __attribute__((ext_vector_type(8)));
typedef float f32x4 __attribute__((ext_vector_type(4)));

static __device__ __forceinline__ f16x2 pkrtz(float a, float b) {
  return __builtin_bit_cast(f16x2, __builtin_amdgcn_cvt_pkrtz(a, b));
}

// async 16B global -> LDS. Dest = wave-uniform base + lane*16 (HW rule).
static __device__ __forceinline__ void gl_lds16(const f16* g, f16* l) {
  __builtin_amdgcn_global_load_lds(
      (const __attribute__((address_space(1))) void*)g,
      (__attribute__((address_space(3))) void*)l, 16, 0, 0);
}

// ---------------- workspace layouts ----------------------------------------
#define SZ_LIST (NEXP*NTOK*4)
#define SZ_WGT  (NEXP*NTOK*4)
#define SZ_MAP  (NTOK*16)
#define SZ_WPR  (NTOK*8)
// fallback path
#define OP_CNT   0
#define OP_OFFS  256
#define OP_LIST  512
#define OP_WGT   (OP_LIST + SZ_LIST)
#define OP_MAP   (OP_WGT + SZ_WGT)
#define OP_WPR   (OP_MAP + SZ_MAP)
#define OP_XH    (OP_WPR + SZ_WPR)
#define OP_H     (OP_XH + (size_t)NTOK*HIDDEN*2)
#define OP_END   (OP_H + (size_t)2*NTOK*INTER*2)
// fast path: tiled f16 weights + compact H
#define NP_CNT   0
#define NP_OFFS  256
#define NP_LIST  512
#define NP_WGT   (NP_LIST + SZ_LIST)
#define NP_MAP   (NP_WGT + SZ_WGT)
#define NP_WPR   (NP_MAP + SZ_MAP)
#define NP_XH    (NP_WPR + SZ_WPR)
#define NP_WGU   (NP_XH + (size_t)NTOK*HIDDEN*2)
#define NP_WDT   (NP_WGU + (size_t)NEXP*2*INTER*HIDDEN*2)
#define NP_H     (NP_WDT + (size_t)NEXP*HIDDEN*INTER*2)
#define NP_C2    (NP_H + (size_t)2*NTOK*INTER*2)
#define NP_END   (NP_C2 + (size_t)2*NTOK*HIDDEN*2)      // ~175 MB

// ---------------- Router ----------------------------------------------------
__global__ __launch_bounds__(256) void moe_router(
    const float* __restrict__ X, const float* __restrict__ Wr,
    f16* __restrict__ Xh, int* __restrict__ cnt,
    int* __restrict__ list, float* __restrict__ wgt,
    int4* __restrict__ map, float2* __restrict__ wpr)
{
  const int t = blockIdx.x, tid = threadIdx.x;
  const float* xrow = X + (size_t)t * HIDDEN;
  const int h0 = tid * 8;
  float4 xa = *(const float4*)(xrow + h0);
  float4 xb = *(const float4*)(xrow + h0 + 4);
  float xs[8] = {xa.x, xa.y, xa.z, xa.w, xb.x, xb.y, xb.z, xb.w};
  f16x8 xh;
#pragma unroll
  for (int j = 0; j < 8; ++j) xh[j] = (f16)xs[j];
  *(f16x8*)(Xh + (size_t)t * HIDDEN + h0) = xh;

  float acc[8] = {0.f,0.f,0.f,0.f,0.f,0.f,0.f,0.f};
#pragma unroll
  for (int j = 0; j < 8; ++j) {
    const float4* wr = (const float4*)(Wr + (size_t)(h0 + j) * NEXP);
    float4 wa = wr[0], wb = wr[1];
    acc[0] += xs[j]*wa.x; acc[1] += xs[j]*wa.y; acc[2] += xs[j]*wa.z; acc[3] += xs[j]*wa.w;
    acc[4] += xs[j]*wb.x; acc[5] += xs[j]*wb.y; acc[6] += xs[j]*wb.z; acc[7] += xs[j]*wb.w;
  }
  const int lane = tid & 63, wid = tid >> 6;
#pragma unroll
  for (int e = 0; e < 8; ++e) {
#pragma unroll
    for (int s = 1; s < 64; s <<= 1) acc[e] += __shfl_xor(acc[e], s, 64);
  }
  __shared__ float red[4][8];
  if (lane == 0) {
#pragma unroll
    for (int e = 0; e < 8; ++e) red[wid][e] = acc[e];
  }
  __syncthreads();
  if (tid == 0) {
    float l[8];
#pragma unroll
    for (int e = 0; e < 8; ++e)
      l[e] = red[0][e] + red[1][e] + red[2][e] + red[3][e];
    int i1 = 0;
#pragma unroll
    for (int e = 1; e < 8; ++e) if (l[e] > l[i1]) i1 = e;
    int i2 = (i1 == 0) ? 1 : 0;
#pragma unroll
    for (int e = 0; e < 8; ++e) if (e != i1 && l[e] > l[i2]) i2 = e;
    float w1 = 1.f / (1.f + expf(l[i2] - l[i1]));
    float w2 = 1.f - w1;
    int p1 = atomicAdd(cnt + i1, 1);
    list[i1*NTOK + p1] = t; wgt[i1*NTOK + p1] = w1;
    int p2 = atomicAdd(cnt + i2, 1);
    list[i2*NTOK + p2] = t; wgt[i2*NTOK + p2] = w2;
    map[t] = make_int4(i1, p1, i2, p2);
    wpr[t] = make_float2(w1, w2);
  }
}

__global__ void moe_scan(const int* __restrict__ cnt, int* __restrict__ offs)
{
  if (threadIdx.x == 0 && blockIdx.x == 0) {
    int s = 0;
    for (int e = 0; e < NEXP; ++e) { offs[e] = s; s += cnt[e]; }
  }
}

// -------- fp32 [E][K][N] -> tiled f16 [e][nb][ks][512 slots x 8 f16] --------
__global__ __launch_bounds__(256) void w_cvt_tile(
    const float* __restrict__ src, f16* __restrict__ dst,
    int K, int N, int nbOfs, int nbTot)
{
  const int ksTot = K >> 5;
  const int e  = blockIdx.y;
  const int nb = blockIdx.x / ksTot;
  const int ks = blockIdx.x - nb * ksTot;
  const int n0 = nb * 128, k0 = ks * 32;
  const float* s = src + (size_t)e * K * N + (size_t)k0 * N + n0;
  f16* d = dst + (((size_t)e * nbTot + nbOfs + nb) * ksTot + ks) * 4096;
  const int t = threadIdx.x;
  __shared__ float lt[32][132];   // 132-float row stride keeps 16B alignment
#pragma unroll
  for (int p = 0; p < 4; ++p) {
    const int idx = p * 256 + t;      // float4 index within the 32x128 tile
    const int row = idx >> 5;         // 32 float4 per row
    const int c4  = idx & 31;
    float4 v = *(const float4*)(s + (size_t)row * N + c4 * 4);
    *(float4*)&lt[row][c4 * 4] = v;
  }
  __syncthreads();
#pragma unroll
  for (int half = 0; half < 2; ++half) {
    const int slot = t + half * 256;
    const int ra = slot >> 2;
    const int kc = (slot & 3) ^ ((ra >> 1) & 3);
    f16x8 hv;
#pragma unroll
    for (int j = 0; j < 4; ++j) {
      f16x2 pk = pkrtz(lt[kc*8 + 2*j][ra], lt[kc*8 + 2*j + 1][ra]);
      hv[2*j] = pk[0]; hv[2*j+1] = pk[1];
    }
    *(f16x8*)(d + (size_t)slot * 8) = hv;
  }
}

// ---- GEMM1 (fused gate+up+silu): H[row][0:1408] = silu(X@Wg)*(X@Wu) --------
// 1D grid + panel->XCD swizzle: all 32 m-blocks of a (e,nb) weight panel run
// on the SAME XCD (bid%8), so the panel is fetched into that L2 exactly once.
__global__ __launch_bounds__(256, 3) void moe_gemm1_f16(
    const f16* __restrict__ Xh, const f16* __restrict__ Wgu,
    f16* __restrict__ H,
    const int* __restrict__ cnt, const int* __restrict__ offs,
    const int* __restrict__ list)
{
  const int bid  = blockIdx.x;
  const int xcd  = bid & 7;
  const int slot = bid >> 3;        // 0..351
  const int P    = (slot >> 5) * 8 + xcd;   // panel id 0..87
  const int mb   = slot & 31;
  const int e    = P / 11;
  const int nb   = P - e * 11;
  const int c    = cnt[e];
  const int m0   = mb * 64;
  if (m0 >= c) return;
  const int n0  = nb * 128;
  const int off = offs[e];
  const int tid = threadIdx.x;

  __shared__ f16 As[64*32];
  __shared__ f16 Bg[128*32];
  __shared__ f16 Bu[128*32];

  const int lane = tid & 63;
  const int w    = tid >> 6;
  const int lrow = lane & 15;
  const int q    = lane >> 4;
  const int wm   = (w & 1) * 32;
  const int wn   = (w >> 1) * 64;

  // A staging: 256 slots cover 64 rows x 32 k
  const int raA = tid >> 2, kcA = (tid & 3) ^ ((raA >> 1) & 3);
  const int tokA = list[e*NTOK + min(m0 + raA, c - 1)];
  const f16* pa = Xh + (size_t)tokA * HIDDEN + kcA*8;
  f16* ldsA = As + (size_t)(w*64)*8;

  // B staging: 512 slots per matrix
  const int s0 = tid, s1 = tid + 256;
  f16* ldsG0 = Bg + (size_t)(w*64)*8;
  f16* ldsG1 = Bg + (size_t)(256 + w*64)*8;
  f16* ldsU0 = Bu + (size_t)(w*64)*8;
  f16* ldsU1 = Bu + (size_t)(256 + w*64)*8;
  const f16* Btg = Wgu + ((size_t)(e*22 + nb)      * (HIDDEN/32)) * 4096;
  const f16* Btu = Wgu + ((size_t)(e*22 + 11 + nb) * (HIDDEN/32)) * 4096;

  f32x4 ag[8], au[8];
#pragma unroll
  for (int i = 0; i < 8; ++i) { ag[i] = (f32x4){0.f,0.f,0.f,0.f}; au[i] = ag[i]; }

  for (int ks = 0; ks < HIDDEN/32; ++ks) {
    __syncthreads();
    gl_lds16(pa + ks*32, ldsA);
    gl_lds16(Btg + (size_t)s0*8, ldsG0);
    gl_lds16(Btg + (size_t)s1*8, ldsG1);
    gl_lds16(Btu + (size_t)s0*8, ldsU0);
    gl_lds16(Btu + (size_t)s1*8, ldsU1);
    Btg += 4096; Btu += 4096;
    __syncthreads();
    f16x8 af[2], gf[4], uf[4];
#pragma unroll
    for (int tm = 0; tm < 2; ++tm) {
      int row = wm + tm*16 + lrow;
      int ch  = q ^ ((row >> 1) & 3);
      af[tm] = *(const f16x8*)(As + row*32 + ch*8);
    }
#pragma unroll
    for (int tn = 0; tn < 4; ++tn) {
      int row = wn + tn*16 + lrow;
      int ch  = q ^ ((row >> 1) & 3);
      gf[tn] = *(const f16x8*)(Bg + row*32 + ch*8);
      uf[tn] = *(const f16x8*)(Bu + row*32 + ch*8);
    }
#pragma unroll
    for (int tm = 0; tm < 2; ++tm)
#pragma unroll
      for (int tn = 0; tn < 4; ++tn) {
        ag[tm*4+tn] = __builtin_amdgcn_mfma_f32_16x16x32_f16(
            af[tm], gf[tn], ag[tm*4+tn], 0, 0, 0);
        au[tm*4+tn] = __builtin_amdgcn_mfma_f32_16x16x32_f16(
            af[tm], uf[tn], au[tm*4+tn], 0, 0, 0);
      }
  }
#pragma unroll
  for (int tm = 0; tm < 2; ++tm)
#pragma unroll
    for (int tn = 0; tn < 4; ++tn)
#pragma unroll
      for (int j = 0; j < 4; ++j) {
        int lr = wm + tm*16 + q*4 + j;
        if (m0 + lr < c) {
          float g = ag[tm*4+tn][j];
          float sgl = g / (1.f + __expf(-g));
          H[(size_t)(off + m0 + lr) * INTER + (n0 + wn + tn*16 + lrow)] =
              (f16)(sgl * au[tm*4+tn][j]);
        }
      }
}

// ---------------- GEMM2: C2[row] = H @ Wd  (compact, unweighted) ------------
__global__ __launch_bounds__(256, 4) void moe_gemm2_f16(
    const f16* __restrict__ H, const f16* __restrict__ Wdt,
    f16* __restrict__ C2,
    const int* __restrict__ cnt, const int* __restrict__ offs)
{
  const int bid  = blockIdx.x;
  const int xcd  = bid & 7;
  const int slot = bid >> 3;        // 0..511
  const int P    = (slot >> 5) * 8 + xcd;   // panel id 0..127
  const int mb   = slot & 31;
  const int e    = P >> 4;
  const int nb   = P & 15;
  const int c    = cnt[e];
  const int m0   = mb * 64;
  if (m0 >= c) return;
  const int n0  = nb * 128;
  const int off = offs[e];
  const int tid = threadIdx.x;

  __shared__ f16 As[64*32];
  __shared__ f16 Bs[128*32];

  const int lane = tid & 63;
  const int w    = tid >> 6;
  const int lrow = lane & 15;
  const int q    = lane >> 4;
  const int wm   = (w & 1) * 32;
  const int wn   = (w >> 1) * 64;

  const int raA = tid >> 2, kcA = (tid & 3) ^ ((raA >> 1) & 3);
  const f16* pa = H + (size_t)(off + min(m0 + raA, c - 1)) * INTER + kcA*8;
  f16* ldsA = As + (size_t)(w*64)*8;

  const int s0 = tid, s1 = tid + 256;
  f16* ldsB0 = Bs + (size_t)(w*64)*8;
  f16* ldsB1 = Bs + (size_t)(256 + w*64)*8;
  const f16* Bt = Wdt + ((size_t)(e*16 + nb) * (INTER/32)) * 4096;

  f32x4 acc[8];
#pragma unroll
  for (int i = 0; i < 8; ++i) acc[i] = (f32x4){0.f,0.f,0.f,0.f};

  for (int ks = 0; ks < INTER/32; ++ks) {
    __syncthreads();
    gl_lds16(pa + ks*32, ldsA);
    gl_lds16(Bt + (size_t)s0*8, ldsB0);
    gl_lds16(Bt + (size_t)s1*8, ldsB1);
    Bt += 4096;
    __syncthreads();
    f16x8 af[2], bf[4];
#pragma unroll
    for (int tm = 0; tm < 2; ++tm) {
      int row = wm + tm*16 + lrow;
      int ch  = q ^ ((row >> 1) & 3);
      af[tm] = *(const f16x8*)(As + row*32 + ch*8);
    }
#pragma unroll
    for (int tn = 0; tn < 4; ++tn) {
      int row = wn + tn*16 + lrow;
      int ch  = q ^ ((row >> 1) & 3);
      bf[tn] = *(const f16x8*)(Bs + row*32 + ch*8);
    }
#pragma unroll
    for (int tm = 0; tm < 2; ++tm)
#pragma unroll
      for (int tn = 0; tn < 4; ++tn)
        acc[tm*4+tn] = __builtin_amdgcn_mfma_f32_16x16x32_f16(
            af[tm], bf[tn], acc[tm*4+tn], 0, 0, 0);
  }
#pragma unroll
  for (int tm = 0; tm < 2; ++tm)
#pragma unroll
    for (int tn = 0; tn < 4; ++tn)
#pragma unroll
      for (int j = 0; j < 4; ++j) {
        int lr = wm + tm*16 + q*4 + j;
        if (m0 + lr < c)
          C2[(size_t)(off + m0 + lr) * HIDDEN + (n0 + wn + tn*16 + lrow)] =
              (f16)acc[tm*4+tn][j];
      }
}

// ---------------- combine: out[t] = w1*C2[r1] + w2*C2[r2] -------------------
__global__ __launch_bounds__(256) void moe_combine(
    const f16* __restrict__ C2, const int4* __restrict__ map,
    const float2* __restrict__ wpr, const int* __restrict__ offs,
    float* __restrict__ out)
{
  const int t = blockIdx.x, tid = threadIdx.x;
  int4 m = map[t];
  float2 wv = wpr[t];
  const size_t r1 = (size_t)(offs[m.x] + m.y) * HIDDEN;
  const size_t r2 = (size_t)(offs[m.z] + m.w) * HIDDEN;
  f16x8 a = *(const f16x8*)(C2 + r1 + tid*8);
  f16x8 b = *(const f16x8*)(C2 + r2 + tid*8);
  float4 o0, o1;
  float* po = out + (size_t)t * HIDDEN + tid*8;
  o0.x = wv.x*(float)a[0] + wv.y*(float)b[0];
  o0.y = wv.x*(float)a[1] + wv.y*(float)b[1];
  o0.z = wv.x*(float)a[2] + wv.y*(float)b[2];
  o0.w = wv.x*(float)a[3] + wv.y*(float)b[3];
  o1.x = wv.x*(float)a[4] + wv.y*(float)b[4];
  o1.y = wv.x*(float)a[5] + wv.y*(float)b[5];
  o1.z = wv.x*(float)a[6] + wv.y*(float)b[6];
  o1.w = wv.x*(float)a[7] + wv.y*(float)b[7];
  *(float4*)po = o0;
  *(float4*)(po + 4) = o1;
}

// ================= fallback (round-2) GEMMs =================================
__global__ __launch_bounds__(256, 2) void moe_gemm1(
    const f16* __restrict__ Xh, const float* __restrict__ Wg,
    const float* __restrict__ Wu, f16* __restrict__ H,
    const int* __restrict__ cnt, const int* __restrict__ offs,
    const int* __restrict__ list)
{
  const int e  = blockIdx.z;
  const int c  = cnt[e];
  const int m0 = blockIdx.y * 128;
  if (m0 >= c) return;
  const int n0  = blockIdx.x * 128;
  const int off = offs[e];
  const int tid = threadIdx.x;

  __shared__ f16 As[128][40];
  __shared__ f16 Bs[128][40];
  __shared__ int tokLds[128];
  if (tid < 128) tokLds[tid] = list[e*NTOK + min(m0 + tid, c - 1)];

  const int lane = tid & 63;
  const int w    = tid >> 6;
  const int lrow = lane & 15;
  const int q    = lane >> 4;
  const int mb   = (w & 1) * 64;
  const int nb   = (w >> 1) * 64;
  const int ar = tid >> 1;
  const int ah = (tid & 1) * 16;
  const int bn = tid & 31;
  const int bk = (tid >> 5) * 4;

  const size_t ebase = (size_t)e * HIDDEN * INTER;
  const float* Wge = Wg + ebase;
  const float* Wue = Wu + ebase;

  f16x4 sg[16];
  f32x4 acc[16];

  for (int pass = 0; pass < 2; ++pass) {
    const float* B = pass ? Wue : Wge;
#pragma unroll
    for (int i = 0; i < 16; ++i) acc[i] = (f32x4){0.f, 0.f, 0.f, 0.f};
    for (int ks = 0; ks < HIDDEN/32; ++ks) {
      const int k0 = ks * 32;
      __syncthreads();
      {
        const uint4* src = (const uint4*)(Xh + (size_t)tokLds[ar] * HIDDEN + k0 + ah);
        uint4 a0 = src[0], a1 = src[1];
        uint2* dst = (uint2*)&As[ar][ah];
        dst[0] = make_uint2(a0.x, a0.y);
        dst[1] = make_uint2(a0.z, a0.w);
        dst[2] = make_uint2(a1.x, a1.y);
        dst[3] = make_uint2(a1.z, a1.w);
      }
#pragma unroll
      for (int g = 0; g < 4; ++g) {
        const int ncol = bn + 32*g;
        const float* bp = B + (size_t)(k0 + bk) * INTER + (n0 + ncol);
        float v0 = bp[0*INTER], v1 = bp[1*INTER], v2 = bp[2*INTER], v3 = bp[3*INTER];
        f16x2 p01 = pkrtz(v0, v1), p23 = pkrtz(v2, v3);
        f16x4 hv; hv[0] = p01[0]; hv[1] = p01[1]; hv[2] = p23[0]; hv[3] = p23[1];
        *(f16x4*)&Bs[ncol][bk] = hv;
      }
      __syncthreads();
      f16x8 af[4], bf[4];
#pragma unroll
      for (int tm = 0; tm < 4; ++tm) {
        const f16* p = &As[mb + tm*16 + lrow][q*8];
        f16x4 lo = *(const f16x4*)p, hi = *(const f16x4*)(p + 4);
        af[tm] = (f16x8){lo[0],lo[1],lo[2],lo[3],hi[0],hi[1],hi[2],hi[3]};
      }
#pragma unroll
      for (int tn = 0; tn < 4; ++tn) {
        const f16* p = &Bs[nb + tn*16 + lrow][q*8];
        f16x4 lo = *(const f16x4*)p, hi = *(const f16x4*)(p + 4);
        bf[tn] = (f16x8){lo[0],lo[1],lo[2],lo[3],hi[0],hi[1],hi[2],hi[3]};
      }
#pragma unroll
      for (int tm = 0; tm < 4; ++tm)
#pragma unroll
        for (int tn = 0; tn < 4; ++tn)
          acc[tm*4+tn] = __builtin_amdgcn_mfma_f32_16x16x32_f16(
              af[tm], bf[tn], acc[tm*4+tn], 0, 0, 0);
    }
    if (pass == 0) {
#pragma unroll
      for (int i = 0; i < 16; ++i)
#pragma unroll
        for (int j = 0; j < 4; ++j) {
          float g = acc[i][j];
          sg[i][j] = (f16)(g / (1.f + __expf(-g)));
        }
    }
  }
#pragma unroll
  for (int tm = 0; tm < 4; ++tm)
#pragma unroll
    for (int tn = 0; tn < 4; ++tn)
#pragma unroll
      for (int j = 0; j < 4; ++j) {
        int lr = mb + tm*16 + q*4 + j;
        if (m0 + lr < c) {
          float h = (float)sg[tm*4+tn][j] * acc[tm*4+tn][j];
          H[(size_t)(off + m0 + lr) * INTER + (n0 + nb + tn*16 + lrow)] = (f16)h;
        }
      }
}

__global__ __launch_bounds__(256, 2) void moe_gemm2(
    const f16* __restrict__ H, const float* __restrict__ Wd,
    float* __restrict__ out,
    const int* __restrict__ cnt, const int* __restrict__ offs,
    const int* __restrict__ list, const float* __restrict__ wgt)
{
  const int e  = blockIdx.z;
  const int c  = cnt[e];
  const int m0 = blockIdx.y * 128;
  if (m0 >= c) return;
  const int n0  = blockIdx.x * 128;
  const int off = offs[e];
  const int tid = threadIdx.x;

  __shared__ f16 As[128][40];
  __shared__ f16 Bs[128][40];
  __shared__ int   tokLds[128];
  __shared__ float wLds[128];
  if (tid < 128) {
    int s = e*NTOK + min(m0 + tid, c - 1);
    tokLds[tid] = list[s];
    wLds[tid]   = wgt[s];
  }
  const int lane = tid & 63;
  const int w    = tid >> 6;
  const int lrow = lane & 15;
  const int q    = lane >> 4;
  const int mb   = (w & 1) * 64;
  const int nb   = (w >> 1) * 64;
  const int ar = tid >> 1;
  const int ah = (tid & 1) * 16;
  const int bn = tid & 31;
  const int bk = (tid >> 5) * 4;

  const int arow = off + min(m0 + ar, c - 1);
  const float* Wde = Wd + (size_t)e * INTER * HIDDEN;

  f32x4 acc[16];
#pragma unroll
  for (int i = 0; i < 16; ++i) acc[i] = (f32x4){0.f, 0.f, 0.f, 0.f};

  for (int ks = 0; ks < INTER/32; ++ks) {
    const int k0 = ks * 32;
    __syncthreads();
    {
      const uint4* src = (const uint4*)(H + (size_t)arow * INTER + k0 + ah);
      uint4 a0 = src[0], a1 = src[1];
      uint2* dst = (uint2*)&As[ar][ah];
      dst[0] = make_uint2(a0.x, a0.y);
      dst[1] = make_uint2(a0.z, a0.w);
      dst[2] = make_uint2(a1.x, a1.y);
      dst[3] = make_uint2(a1.z, a1.w);
    }
#pragma unroll
    for (int g = 0; g < 4; ++g) {
      const int ncol = bn + 32*g;
      const float* bp = Wde + (size_t)(k0 + bk) * HIDDEN + (n0 + ncol);
      float v0 = bp[0*HIDDEN], v1 = bp[1*HIDDEN], v2 = bp[2*HIDDEN], v3 = bp[3*HIDDEN];
      f16x2 p01 = pkrtz(v0, v1), p23 = pkrtz(v2, v3);
      f16x4 hv; hv[0] = p01[0]; hv[1] = p01[1]; hv[2] = p23[0]; hv[3] = p23[1];
      *(f16x4*)&Bs[ncol][bk] = hv;
    }
    __syncthreads();
    f16x8 af[4], bf[4];
#pragma unroll
    for (int tm = 0; tm < 4; ++tm) {
      const f16* p = &As[mb + tm*16 + lrow][q*8];
      f16x4 lo = *(const f16x4*)p, hi = *(const f16x4*)(p + 4);
      af[tm] = (f16x8){lo[0],lo[1],lo[2],lo[3],hi[0],hi[1],hi[2],hi[3]};
    }
#pragma unroll
    for (int tn = 0; tn < 4; ++tn) {
      const f16* p = &Bs[nb + tn*16 + lrow][q*8];
      f16x4 lo = *(const f16x4*)p, hi = *(const f16x4*)(p + 4);
      bf[tn] = (f16x8){lo[0],lo[1],lo[2],lo[3],hi[0],hi[1],hi[2],hi[3]};
    }
#pragma unroll
    for (int tm = 0; tm < 4; ++tm)
#pragma unroll
      for (int tn = 0; tn < 4; ++tn)
        acc[tm*4+tn] = __builtin_amdgcn_mfma_f32_16x16x32_f16(
            af[tm], bf[tn], acc[tm*4+tn], 0, 0, 0);
  }
#pragma unroll
  for (int tm = 0; tm < 4; ++tm)
#pragma unroll
    for (int tn = 0; tn < 4; ++tn)
#pragma unroll
      for (int j = 0; j < 4; ++j) {
        int lr = mb + tm*16 + q*4 + j;
        if (m0 + lr < c) {
          float v = acc[tm*4+tn][j] * wLds[lr];
          atomicAdd(out + (size_t)tokLds[lr] * HIDDEN + (n0 + nb + tn*16 + lrow), v);
        }
      }
}

// ---------------- launch ----------------------------------------------------
extern "C" void kernel_launch(void* const* d_in, const int* in_sizes, int n_in,
                              void* d_out, int out_size, void* d_ws, size_t ws_size,
                              hipStream_t stream)
{
  const float* X  = (const float*)d_in[0];
  const float* Wr = (const float*)d_in[1];
  const float* Wg = (const float*)d_in[2];
  const float* Wu = (const float*)d_in[3];
  const float* Wd = (const float*)d_in[4];
  float* out = (float*)d_out;
  char* ws   = (char*)d_ws;

  if (ws_size >= (size_t)NP_END) {
    int*    cnt  = (int*)(ws + NP_CNT);
    int*    offs = (int*)(ws + NP_OFFS);
    int*    list = (int*)(ws + NP_LIST);
    float*  wgt  = (float*)(ws + NP_WGT);
    int4*   map  = (int4*)(ws + NP_MAP);
    float2* wpr  = (float2*)(ws + NP_WPR);
    f16*    Xh   = (f16*)(ws + NP_XH);
    f16*    Wgu  = (f16*)(ws + NP_WGU);
    f16*    Wdt  = (f16*)(ws + NP_WDT);
    f16*    H    = (f16*)(ws + NP_H);
    f16*    C2   = (f16*)(ws + NP_C2);

    (void)hipMemsetAsync(cnt, 0, NEXP * sizeof(int), stream);
    moe_router<<<NTOK, 256, 0, stream>>>(X, Wr, Xh, cnt, list, wgt, map, wpr);
    moe_scan<<<1, 64, 0, stream>>>(cnt, offs);
    // gate -> Wgu nblk 0..10, up -> nblk 11..21, down -> Wdt nblk 0..15
    w_cvt_tile<<<dim3(11 * (HIDDEN/32), NEXP), 256, 0, stream>>>(
        Wg, Wgu, HIDDEN, INTER, 0, 22);
    w_cvt_tile<<<dim3(11 * (HIDDEN/32), NEXP), 256, 0, stream>>>(
        Wu, Wgu, HIDDEN, INTER, 11, 22);
    w_cvt_tile<<<dim3(16 * (INTER/32), NEXP), 256, 0, stream>>>(
        Wd, Wdt, INTER, HIDDEN, 0, 16);
    // 1D swizzled grids: 8 XCD * (panels/XCD) * 32 m-blocks
    moe_gemm1_f16<<<8 * 11 * 32, 256, 0, stream>>>(
        Xh, Wgu, H, cnt, offs, list);
    moe_gemm2_f16<<<8 * 16 * 32, 256, 0, stream>>>(
        H, Wdt, C2, cnt, offs);
    moe_combine<<<NTOK, 256, 0, stream>>>(C2, map, wpr, offs, out);
  } else {
    int*   cnt  = (int*)(ws + OP_CNT);
    int*   offs = (int*)(ws + OP_OFFS);
    int*   list = (int*)(ws + OP_LIST);
    float* wgt  = (float*)(ws + OP_WGT);
    int4*  map  = (int4*)(ws + OP_MAP);
    float2* wpr = (float2*)(ws + OP_WPR);
    f16*   Xh   = (f16*)(ws + OP_XH);
    f16*   H    = (f16*)(ws + OP_H);

    (void)hipMemsetAsync(cnt, 0, NEXP * sizeof(int), stream);
    (void)hipMemsetAsync(out, 0, (size_t)NTOK * HIDDEN * sizeof(float), stream);
    moe_router<<<NTOK, 256, 0, stream>>>(X, Wr, Xh, cnt, list, wgt, map, wpr);
    moe_scan<<<1, 64, 0, stream>>>(cnt, offs);
    moe_gemm1<<<dim3(INTER/128, NTOK/128, NEXP), 256, 0, stream>>>(
        Xh, Wg, Wu, H, cnt, offs, list);
    moe_gemm2<<<dim3(HIDDEN/128, NTOK/128, NEXP), 256, 0, stream>>>(
        H, Wd, out, cnt, offs, list, wgt);
  }
}